// Round 1
// baseline (332.947 us; speedup 1.0000x reference)
//
#include <hip/hip_runtime.h>

// Problem constants (from reference)
constexpr int B = 4, N = 1024, M = 64, H = 32, W = 32;
constexpr float EXPAND = 1.2f;
constexpr float TWO_SIG2 = 2.0f * 1.6f * 1.6f;   // 5.12
constexpr float GAUSS_THR = 0.6f;
constexpr float GAUSS_3D_THR = 0.5f;             // == GAUSS_DEPTH_THR, masks identical
constexpr int HW = H * W;                         // 1024
constexpr size_t S = (size_t)B * N * HW;          // per-channel stride = 4,194,304

// Output layout (flat concat, in reference return order), in units of S:
//  0: cls_label (1ch)   1: cls_label_w (1ch)
//  2: reg_2d (2ch)      4: reg_2d_w (2ch)
//  6: reg_3d (2ch)      8: reg_3d_w (2ch)
// 10: depth_label (1)  11: depth_label_w (1)
// 12: dim_label (3)    15: dim_label_w (3)
// 18: rot_label (1)    19: rot_label_w (1)

__global__ __launch_bounds__(256)
void rcnn3d_label_kernel(const float* __restrict__ boxes,      // (B,N,4)
                         const float* __restrict__ gt_boxes,   // (B,M,14)
                         const int*   __restrict__ pos_flag,   // (B,N)
                         const int*   __restrict__ gt_id,      // (B,N)
                         float* __restrict__ out)
{
    const int bn  = blockIdx.x;       // b*N + n
    const int b   = bn >> 10;         // N = 1024
    const int tid = threadIdx.x;

    // ---- per-(b,n) block-uniform scalars (compiler scalarizes these) ----
    const float4 bx = *reinterpret_cast<const float4*>(boxes + (size_t)bn * 4);
    const int   gid = gt_id[bn];
    const float* g  = gt_boxes + ((size_t)b * M + gid) * 14;
    const float kxg = g[4], kyg = g[5], klab = g[6];
    const float dim0 = g[7], dim1 = g[8], dim2 = g[9];
    const float depth = g[12], rot = g[13];
    const bool valid = (klab != 0.0f) && (pos_flag[bn] > 0);

    // replicate reference float-op order exactly
    const float cx = 0.5f * (bx.x + bx.z);
    const float cy = 0.5f * (bx.y + bx.w);
    const float hw = 0.5f * (bx.z - bx.x) * EXPAND;
    const float hh = 0.5f * (bx.w - bx.y) * EXPAND;
    const float ex1 = cx - hw, ey1 = cy - hh;
    const float ex2 = cx + hw, ey2 = cy + hh;
    const float sx = (float)W / (ex2 - ex1 + 1.0f);
    const float sy = (float)H / (ey2 - ey1 + 1.0f);
    const float kx = (kxg - ex1) * sx;
    const float ky = (kyg - ey1) * sy;

    // ---- 4 consecutive cells per thread (same row), float4-aligned ----
    const int h  = tid >> 3;          // (tid*4)/32
    const int w0 = (tid & 7) * 4;
    const float gy   = (float)h;
    const float offy = ky - gy;
    const float dy   = gy + 0.5f - ky;
    const float dy2  = dy * dy;

    float score[4], offx[4];
    bool  m2[4], m3[4];
    bool  any2 = false;
#pragma unroll
    for (int j = 0; j < 4; ++j) {
        const float gx = (float)(w0 + j);
        const float dx = gx + 0.5f - kx;
        const float s  = expf(-((dx * dx + dy2) / TWO_SIG2));
        score[j] = s;
        offx[j]  = kx - gx;
        m2[j] = (s >= GAUSS_THR)    && valid;
        m3[j] = (s >= GAUSS_3D_THR) && valid;
        any2 |= m2[j];
    }

    // ---- block-wide any(m2): shared flag (benign same-value race) ----
    __shared__ int s_has;
    if (tid == 0) s_has = 0;
    __syncthreads();
    if (any2) s_has = 1;
    __syncthreads();
    const bool has = (s_has != 0);

    // ---- assemble float4 payloads ----
    float4 v_cls, v_clsw, v_rx2, v_ry2, v_w2, v_rx3, v_ry3, v_w3;
    float4 v_dep, v_d0, v_d1, v_d2, v_rot;
#pragma unroll
    for (int j = 0; j < 4; ++j) {
        const float f2 = m2[j] ? 1.0f : 0.0f;
        const float f3 = m3[j] ? 1.0f : 0.0f;
        (&v_cls.x)[j]  = has ? score[j] : -1.0f;
        (&v_clsw.x)[j] = has ? 1.0f : 0.0f;
        (&v_rx2.x)[j]  = offx[j] * f2;
        (&v_ry2.x)[j]  = offy    * f2;
        (&v_w2.x)[j]   = f2;
        (&v_rx3.x)[j]  = offx[j] * f3;
        (&v_ry3.x)[j]  = offy    * f3;
        (&v_w3.x)[j]   = f3;
        (&v_dep.x)[j]  = depth * f3;
        (&v_d0.x)[j]   = dim0 * f3;
        (&v_d1.x)[j]   = dim1 * f3;
        (&v_d2.x)[j]   = dim2 * f3;
        (&v_rot.x)[j]  = rot * f3;
    }

    // ---- coalesced float4 stores: 20 channels ----
    const size_t cell = (size_t)tid * 4;
    const size_t bn1  = (size_t)bn * HW;        // 1-channel outputs
    const size_t bn2  = (size_t)bn * 2 * HW;    // 2-channel outputs
    const size_t bn3  = (size_t)bn * 3 * HW;    // 3-channel outputs
    auto st = [&](size_t ofs, const float4& v) {
        *reinterpret_cast<float4*>(out + ofs + cell) = v;
    };

    st( 0 * S + bn1,            v_cls);   // cls_label
    st( 1 * S + bn1,            v_clsw);  // cls_label_w
    st( 2 * S + bn2,            v_rx2);   // reg_2d[0]
    st( 2 * S + bn2 + HW,       v_ry2);   // reg_2d[1]
    st( 4 * S + bn2,            v_w2);    // reg_2d_w[0]
    st( 4 * S + bn2 + HW,       v_w2);    // reg_2d_w[1]
    st( 6 * S + bn2,            v_rx3);   // reg_3d[0]
    st( 6 * S + bn2 + HW,       v_ry3);   // reg_3d[1]
    st( 8 * S + bn2,            v_w3);    // reg_3d_w[0]
    st( 8 * S + bn2 + HW,       v_w3);    // reg_3d_w[1]
    st(10 * S + bn1,            v_dep);   // depth_label
    st(11 * S + bn1,            v_w3);    // depth_label_w (== mdf == m3f)
    st(12 * S + bn3,            v_d0);    // dim_label[0]
    st(12 * S + bn3 + HW,       v_d1);    // dim_label[1]
    st(12 * S + bn3 + 2 * HW,   v_d2);    // dim_label[2]
    st(15 * S + bn3,            v_w3);    // dim_label_w[0]
    st(15 * S + bn3 + HW,       v_w3);    // dim_label_w[1]
    st(15 * S + bn3 + 2 * HW,   v_w3);    // dim_label_w[2]
    st(18 * S + bn1,            v_rot);   // rot_label
    st(19 * S + bn1,            v_w3);    // rot_label_w
}

extern "C" void kernel_launch(void* const* d_in, const int* in_sizes, int n_in,
                              void* d_out, int out_size, void* d_ws, size_t ws_size,
                              hipStream_t stream) {
    const float* boxes    = (const float*)d_in[0];
    const float* gt_boxes = (const float*)d_in[1];
    const int*   pos_flag = (const int*)d_in[2];
    const int*   gt_id    = (const int*)d_in[3];
    float*       out      = (float*)d_out;

    rcnn3d_label_kernel<<<dim3(B * N), dim3(256), 0, stream>>>(
        boxes, gt_boxes, pos_flag, gt_id, out);
}